// Round 2
// baseline (321.043 us; speedup 1.0000x reference)
//
#include <hip/hip_runtime.h>
#include <hip/hip_bf16.h>

// BiAttention fused kernels, round 2: 32x32x16 MFMA flash core.
// att[b,l,m] = idot[l] + mdot[m] + cross[l,m]; softmax_m invariant to idot;
// |S'| small -> exp without max subtraction; M-split=2 partials additive.

typedef __bf16 bf16_t;
typedef bf16_t bf16x4 __attribute__((ext_vector_type(4)));
typedef bf16_t bf16x8 __attribute__((ext_vector_type(8)));
typedef float  f32x4  __attribute__((ext_vector_type(4)));
typedef float  f32x16 __attribute__((ext_vector_type(16)));

#define NB 8
#define NL 2048
#define NM 2048
#define ND 256
#define OUTW 1024
#define MT 64            // m per iteration
#define MH 1024          // m per half (M-split = 2)
#define NIT (MH / MT)    // 16
#define LT 128           // L rows per block
#define SK 264           // mem_lds row stride (bf16), 64 rows
#define ST 72            // memT / p_lds row stride (bf16)
#define LDS_BYTES (MT * SK * 2 + ND * ST * 2 + 4 * 32 * ST * 2)  // 89088

// ---------------- Kernel A: input_dot / memory_dot (+mask bias) -------------
__global__ __launch_bounds__(256) void dots_kernel(
    const float* __restrict__ input, const float* __restrict__ memory,
    const float* __restrict__ mask, const float* __restrict__ w_input,
    const float* __restrict__ w_memory,
    float* __restrict__ ws_idot, float* __restrict__ ws_mbias)
{
    int gid  = blockIdx.x * 4 + (threadIdx.x >> 6);
    int lane = threadIdx.x & 63;
    bool is_mem = gid >= NB * NL;
    int row = is_mem ? gid - NB * NL : gid;
    const float* src = (is_mem ? memory : input) + (size_t)row * ND + lane * 4;
    const float* w   = (is_mem ? w_memory : w_input) + lane * 4;
    float4 v = *(const float4*)src;
    float4 wv = *(const float4*)w;
    float s = v.x * wv.x + v.y * wv.y + v.z * wv.z + v.w * wv.w;
    #pragma unroll
    for (int off = 1; off < 64; off <<= 1) s += __shfl_xor(s, off, 64);
    if (lane == 0) {
        if (is_mem) ws_mbias[row] = s - 1e30f * (1.0f - mask[row]);
        else        ws_idot[row]  = s;
    }
}

// ---------------- Kernel B: flash attention partials (32x32x16 MFMA) --------
// grid 256 = lt*16 + b*2 + half (stride-16 blocks share (b,half) -> same XCD).
// block: 4 waves; wave w owns L-rows [w*32, w*32+32), all 256 d.
// Per iter: stage K/V tile (64 m), QK (2 m-subtiles), exp->P (wave-local LDS),
// PV + ones-MFMA l-sum. Raw O partial -> out seg 1/2.
__global__ __launch_bounds__(256, 1) void flash_kernel(
    const float* __restrict__ input, const float* __restrict__ memory,
    const float* __restrict__ dot_scale, const float* __restrict__ ws_mbias,
    float* __restrict__ out, float* __restrict__ ws_l, float* __restrict__ ws_m)
{
    extern __shared__ __align__(16) char smem[];
    bf16_t* mem_lds = (bf16_t*)smem;                       // [64][SK]
    bf16_t* memT    = mem_lds + MT * SK;                   // [256][ST]
    bf16_t* p_lds   = memT + ND * ST;                      // [4][32][ST]

    int bid  = blockIdx.x;
    int half = bid & 1;
    int b    = (bid >> 1) & 7;
    int lt   = bid >> 4;
    int l0   = lt * LT;
    int m_base = half * MH;

    int t    = threadIdx.x;
    int w    = t >> 6;
    int lane = t & 63;
    int c    = lane & 31;
    int h    = lane >> 5;
    int dgrp = t & 63;      // staging: d column group (4 d)
    int mgrp = t >> 6;      // staging: m row group (16 m)

    // ---- Q fragments: A-layout, rows w*32 + c, k = ks*16 + h*8 + j ----
    const float* qrow = input + (size_t)(b * NL + l0 + w * 32 + c) * ND;
    bf16x8 qf[16];
    #pragma unroll
    for (int ks = 0; ks < 16; ++ks) {
        int d0 = ks * 16 + h * 8;
        float4 a0 = *(const float4*)(qrow + d0);
        float4 a1 = *(const float4*)(qrow + d0 + 4);
        float4 s0 = *(const float4*)(dot_scale + d0);
        float4 s1 = *(const float4*)(dot_scale + d0 + 4);
        qf[ks][0] = (bf16_t)(a0.x * s0.x); qf[ks][1] = (bf16_t)(a0.y * s0.y);
        qf[ks][2] = (bf16_t)(a0.z * s0.z); qf[ks][3] = (bf16_t)(a0.w * s0.w);
        qf[ks][4] = (bf16_t)(a1.x * s1.x); qf[ks][5] = (bf16_t)(a1.y * s1.y);
        qf[ks][6] = (bf16_t)(a1.z * s1.z); qf[ks][7] = (bf16_t)(a1.w * s1.w);
    }
    bf16x8 ones;
    #pragma unroll
    for (int j = 0; j < 8; ++j) ones[j] = (bf16_t)1.0f;

    f32x16 oacc[8];
    #pragma unroll
    for (int i = 0; i < 8; ++i)
        #pragma unroll
        for (int r = 0; r < 16; ++r) oacc[i][r] = 0.f;
    f32x16 lacc;
    #pragma unroll
    for (int r = 0; r < 16; ++r) lacc[r] = 0.f;
    float mpart[16];
    #pragma unroll
    for (int r = 0; r < 16; ++r) mpart[r] = -3e38f;

    const float* memb    = memory + (size_t)b * NM * ND;
    const float* mbias_b = ws_mbias + b * NM;
    bf16_t* pw = p_lds + w * 32 * ST;

    // prefetch tile 0
    float4 pf[16];
    {
        const float* src = memb + (size_t)(m_base + mgrp * 16) * ND + dgrp * 4;
        #pragma unroll
        for (int i = 0; i < 16; ++i) pf[i] = *(const float4*)(src + (size_t)i * ND);
    }

    #pragma unroll 1
    for (int it = 0; it < NIT; ++it) {
        int m0 = m_base + it * MT;
        __syncthreads();           // prev iter's LDS reads complete
        // ---- stage: row-major mem_lds (b64 writes) ----
        #pragma unroll
        for (int i = 0; i < 16; ++i) {
            bf16x4 v;
            v[0] = (bf16_t)pf[i].x; v[1] = (bf16_t)pf[i].y;
            v[2] = (bf16_t)pf[i].z; v[3] = (bf16_t)pf[i].w;
            *(bf16x4*)(&mem_lds[(mgrp * 16 + i) * SK + dgrp * 4]) = v;
        }
        // ---- stage: transposed memT (b128 writes, dd-rotated for banks) ----
        #pragma unroll
        for (int ddr = 0; ddr < 4; ++ddr) {
            int dd = (ddr + dgrp) & 3;
            bf16x8 lo, hi;
            #pragma unroll
            for (int i = 0; i < 8; ++i) {
                lo[i] = (bf16_t)((const float*)&pf[i])[dd];
                hi[i] = (bf16_t)((const float*)&pf[8 + i])[dd];
            }
            bf16_t* dst = &memT[(dgrp * 4 + dd) * ST + mgrp * 16];
            *(bf16x8*)dst = lo;
            *(bf16x8*)(dst + 8) = hi;
        }
        __syncthreads();           // staging visible
        // prefetch next tile (overlaps with QK/PV below)
        if (it + 1 < NIT) {
            const float* src = memb + (size_t)(m0 + MT + mgrp * 16) * ND + dgrp * 4;
            #pragma unroll
            for (int i = 0; i < 16; ++i) pf[i] = *(const float4*)(src + (size_t)i * ND);
        }
        // ---- QK: S' = Q.K^T, 2 m-subtiles, K=256 in 16 steps ----
        f32x16 S0, S1;
        #pragma unroll
        for (int r = 0; r < 16; ++r) { S0[r] = 0.f; S1[r] = 0.f; }
        #pragma unroll
        for (int ks = 0; ks < 16; ++ks) {
            bf16x8 b0 = *(const bf16x8*)(&mem_lds[c * SK + ks * 16 + h * 8]);
            bf16x8 b1 = *(const bf16x8*)(&mem_lds[(32 + c) * SK + ks * 16 + h * 8]);
            S0 = __builtin_amdgcn_mfma_f32_32x32x16_bf16(qf[ks], b0, S0, 0, 0, 0);
            S1 = __builtin_amdgcn_mfma_f32_32x32x16_bf16(qf[ks], b1, S1, 0, 0, 0);
        }
        float mb0 = mbias_b[m0 + c];
        float mb1 = mbias_b[m0 + 32 + c];
        // ---- P = exp(S' + mdot), C-layout -> wave-local LDS (row-major) ----
        #pragma unroll
        for (int r = 0; r < 16; ++r) {
            int row = (r & 3) + 8 * (r >> 2) + 4 * h;
            float v0 = S0[r] + mb0, v1 = S1[r] + mb1;
            mpart[r] = fmaxf(mpart[r], fmaxf(v0, v1));
            pw[row * ST + c]      = (bf16_t)__expf(v0);
            pw[row * ST + 32 + c] = (bf16_t)__expf(v1);
        }
        asm volatile("s_waitcnt lgkmcnt(0)" ::: "memory");  // wave-local P ready
        // ---- PV + l-sum: A = P (4 K-steps over m=64), B = memT d-tiles ----
        #pragma unroll
        for (int ks = 0; ks < 4; ++ks) {
            bf16x8 pa = *(const bf16x8*)(&pw[c * ST + ks * 16 + h * 8]);
            lacc = __builtin_amdgcn_mfma_f32_32x32x16_bf16(pa, ones, lacc, 0, 0, 0);
            #pragma unroll
            for (int dt = 0; dt < 8; ++dt) {
                bf16x8 bv = *(const bf16x8*)(&memT[(dt * 32 + c) * ST + ks * 16 + h * 8]);
                oacc[dt] = __builtin_amdgcn_mfma_f32_32x32x16_bf16(pa, bv, oacc[dt], 0, 0, 0);
            }
        }
    }

    // ---- row-max butterfly across the 32 cols (within h-group) ----
    #pragma unroll
    for (int off = 1; off < 32; off <<= 1) {
        #pragma unroll
        for (int r = 0; r < 16; ++r)
            mpart[r] = fmaxf(mpart[r], __shfl_xor(mpart[r], off, 64));
    }
    if (c == 0) {
        #pragma unroll
        for (int r = 0; r < 16; ++r) {
            int row = b * NL + l0 + w * 32 + (r & 3) + 8 * (r >> 2) + 4 * h;
            ws_l[half * (NB * NL) + row] = lacc[r];
            ws_m[half * (NB * NL) + row] = mpart[r];
        }
    }
    // ---- raw O partial -> out seg 1 (half 0) / seg 2 (half 1) ----
    float* oseg = out + (size_t)(b * NL + l0 + w * 32) * OUTW + ND * (1 + half);
    #pragma unroll
    for (int dt = 0; dt < 8; ++dt)
        #pragma unroll
        for (int r = 0; r < 16; ++r) {
            int row = (r & 3) + 8 * (r >> 2) + 4 * h;
            oseg[(size_t)row * OUTW + dt * 32 + c] = oacc[dt][r];
        }
}

// ---------------- Kernel D1: weight_two softmax over L ----------------------
__global__ __launch_bounds__(256) void w2_kernel(
    const float* __restrict__ ws_idot, const float* __restrict__ ws_m,
    float* __restrict__ ws_w2)
{
    int b = blockIdx.x, t = threadIdx.x;
    __shared__ float red[256];
    float vals[8];
    float mx = -3e38f;
    #pragma unroll
    for (int i = 0; i < 8; ++i) {
        int l = i * 256 + t;
        float v = ws_idot[b * NL + l] +
                  fmaxf(ws_m[b * NL + l], ws_m[NB * NL + b * NL + l]);
        vals[i] = v;
        mx = fmaxf(mx, v);
    }
    red[t] = mx; __syncthreads();
    for (int s = 128; s > 0; s >>= 1) {
        if (t < s) red[t] = fmaxf(red[t], red[t + s]);
        __syncthreads();
    }
    mx = red[0]; __syncthreads();
    float se = 0.f;
    #pragma unroll
    for (int i = 0; i < 8; ++i) { vals[i] = __expf(vals[i] - mx); se += vals[i]; }
    red[t] = se; __syncthreads();
    for (int s = 128; s > 0; s >>= 1) {
        if (t < s) red[t] += red[t + s];
        __syncthreads();
    }
    float inv = 1.0f / red[0];
    #pragma unroll
    for (int i = 0; i < 8; ++i) ws_w2[b * NL + i * 256 + t] = vals[i] * inv;
}

// ---------------- Kernel D2: output_two = sum_l w2[l]*input[l,:] ------------
__global__ __launch_bounds__(256) void o2_kernel(
    const float* __restrict__ input, const float* __restrict__ ws_w2,
    float* __restrict__ ws_o2)
{
    int b = blockIdx.x >> 5, slice = blockIdx.x & 31;
    int dq = threadIdx.x & 63, lq = threadIdx.x >> 6;
    float4 acc = {0.f, 0.f, 0.f, 0.f};
    #pragma unroll
    for (int i = 0; i < 16; ++i) {
        int l = slice * 64 + lq * 16 + i;
        float wgt = ws_w2[b * NL + l];
        float4 v = *(const float4*)(input + (size_t)(b * NL + l) * ND + dq * 4);
        acc.x += wgt * v.x; acc.y += wgt * v.y;
        acc.z += wgt * v.z; acc.w += wgt * v.w;
    }
    float* dst = ws_o2 + b * ND + dq * 4;
    atomicAdd(dst + 0, acc.x); atomicAdd(dst + 1, acc.y);
    atomicAdd(dst + 2, acc.z); atomicAdd(dst + 3, acc.w);
}

// ---------------- Kernel E: combine halves + assemble all 4 segments --------
__global__ __launch_bounds__(256) void assembly_kernel(
    const float* __restrict__ input, const float* __restrict__ ws_o2,
    const float* __restrict__ ws_l, float* __restrict__ out)
{
    size_t tid = (size_t)blockIdx.x * 256 + threadIdx.x;
    size_t row = tid >> 6;
    int d = (int)(tid & 63) * 4;
    int b = (int)(row >> 11);
    float inv = 1.0f / (ws_l[row] + ws_l[NB * NL + row]);
    float* po = out + row * OUTW;
    float4 in = *(const float4*)(input + row * ND + d);
    float4 pa = *(const float4*)(po + ND + d);
    float4 pb = *(const float4*)(po + 2 * ND + d);
    float4 o1;
    o1.x = (pa.x + pb.x) * inv; o1.y = (pa.y + pb.y) * inv;
    o1.z = (pa.z + pb.z) * inv; o1.w = (pa.w + pb.w) * inv;
    float4 o2v = *(const float4*)(ws_o2 + b * ND + d);
    *(float4*)(po + d) = in;
    *(float4*)(po + ND + d) = o1;
    float4 q; q.x = in.x * o1.x; q.y = in.y * o1.y; q.z = in.z * o1.z; q.w = in.w * o1.w;
    *(float4*)(po + 2 * ND + d) = q;
    float4 r; r.x = o2v.x * o1.x; r.y = o2v.y * o1.y; r.z = o2v.z * o1.z; r.w = o2v.w * o1.w;
    *(float4*)(po + 3 * ND + d) = r;
}

// ---------------- launcher ---------------------------------------------------
extern "C" void kernel_launch(void* const* d_in, const int* in_sizes, int n_in,
                              void* d_out, int out_size, void* d_ws, size_t ws_size,
                              hipStream_t stream) {
    const float* input     = (const float*)d_in[0];
    const float* memory    = (const float*)d_in[1];
    const float* mask      = (const float*)d_in[2];
    const float* w_input   = (const float*)d_in[3];
    const float* w_memory  = (const float*)d_in[4];
    const float* dot_scale = (const float*)d_in[5];
    float* out = (float*)d_out;
    float* ws  = (float*)d_ws;

    // ws floats: idot 16K | mbias 16K | l 2x16K | m 2x16K | w2 16K | o2 2K
    float* ws_idot  = ws;
    float* ws_mbias = ws + 16384;
    float* ws_l     = ws + 32768;
    float* ws_m     = ws + 65536;
    float* ws_w2    = ws + 98304;
    float* ws_o2    = ws + 114688;

    dots_kernel<<<8192, 256, 0, stream>>>(input, memory, mask, w_input, w_memory,
                                          ws_idot, ws_mbias);
    flash_kernel<<<256, 256, LDS_BYTES, stream>>>(input, memory, dot_scale,
                                                  ws_mbias, out, ws_l, ws_m);
    w2_kernel<<<8, 256, 0, stream>>>(ws_idot, ws_m, ws_w2);
    hipMemsetAsync(ws_o2, 0, NB * ND * sizeof(float), stream);
    o2_kernel<<<256, 256, 0, stream>>>(input, ws_w2, ws_o2);
    assembly_kernel<<<4096, 256, 0, stream>>>(input, ws_o2, ws_l, out);
}